// Round 17
// baseline (169.893 us; speedup 1.0000x reference)
//
#include <hip/hip_runtime.h>

// DomDepResidualLayer: out = relu(h0 + (mixed @ we1^T + b1))
//   enc   = h0 @ we0^T + b0                         [16384,128]
//   acts  = relu(einsum('nd,mkd->mnk', enc, wm)+bm) (never materialized)
//   gate  = softmax(enc @ ws^T + bs, axis=0)        [16384,128]
//   mixed[n,i] = sum_j acts[i,n,j]*gate[n,j]        [16384,128]
// v18 = banked v17 (158.2us, k_mix 75.4 MfmaUtil 37%) + ONE isolated change:
// k_dec panel moves to LDS (32KB, k_enc-style XOR swizzle) -> ~135 VGPR ->
// 3 waves/SIMD, grid 768 -> 12 waves/CU to hide the h0 HBM stream latency.
// Everything else byte-identical to v17.

#define N_TOK   16384
#define EMB     1024
#define MDIM    128

typedef __attribute__((ext_vector_type(8))) short   short8;   // 8 bf16 = 1 bf16 MFMA frag
typedef __attribute__((ext_vector_type(4))) float   f32x4;
typedef __attribute__((ext_vector_type(4))) float   fv4;
typedef __attribute__((ext_vector_type(4))) unsigned short us4;

static __device__ __forceinline__ unsigned short f2bf(float f) {
    union { float f; unsigned u; } v; v.f = f;
    unsigned r = v.u + 0x7FFFu + ((v.u >> 16) & 1u);   // RNE
    return (unsigned short)(r >> 16);
}
static __device__ __forceinline__ float bf2f_lo(unsigned u) {
    union { unsigned u; float f; } v; v.u = u << 16; return v.f;
}
static __device__ __forceinline__ float bf2f_hi(unsigned u) {
    union { unsigned u; float f; } v; v.u = u & 0xffff0000u; return v.f;
}

// ---------------- fused weight conversion: wm -> fp8, we0/we1/ws -> bf16 ----------------
__global__ void k_convert_all(const float* __restrict__ wm_w,
                              const float* __restrict__ we0_w,
                              const float* __restrict__ we1_w,
                              const float* __restrict__ ws_w,
                              unsigned* __restrict__ wmf8,
                              unsigned short* __restrict__ bf16dst) {
    const int N = 524288 + 36864;
    for (int i = blockIdx.x * blockDim.x + threadIdx.x; i < N;
         i += gridDim.x * blockDim.x) {
        if (i < 524288) {                       // wm -> fp8 e4m3, 4 vals per u32
            fv4 v = *(const fv4*)(wm_w + (size_t)i * 4);
            int pk = __builtin_amdgcn_cvt_pk_fp8_f32(v.x, v.y, 0, false);
            pk = __builtin_amdgcn_cvt_pk_fp8_f32(v.z, v.w, pk, true);
            wmf8[i] = (unsigned)pk;
        } else {                                // we0|we1|ws -> bf16
            int j = i - 524288;
            const float* src;
            if (j < 32768)      src = we0_w + (size_t)j * 4;
            else if (j < 65536) src = we1_w + (size_t)(j - 32768) * 4;
            else                src = ws_w  + (size_t)(j - 65536) * 4;
            fv4 v = *(const fv4*)src;
            us4 o;
            o.x = f2bf(v.x); o.y = f2bf(v.y); o.z = f2bf(v.z); o.w = f2bf(v.w);
            *(us4*)(bf16dst + (size_t)j * 4) = o;
        }
    }
}

// encF8 fp8 tile layout (2048 B per 16-tok tile), per-lane-contiguous:
//   byte(tok, d) = tile*2048 + (((d&31)>>3)*16 + tok)*32 + (d>>5)*8 + (d&7)
// gateT bf16 tile layout (2048 bf16 per tile):
//   elem(tok, j=f*16+4g+rr) = tile*2048 + (f>>1)*512 + (g*16 + (tok&15))*8 + (f&1)*4 + rr

// ---------------- enc = h0 @ we0^T + b0 (fp8 out), fused logits = enc @ ws^T + bs ----------------
__global__ __launch_bounds__(256) void k_enc(const float* __restrict__ h0,
                                             const unsigned short* __restrict__ we0b,
                                             const unsigned short* __restrict__ wsb,
                                             const float* __restrict__ we0_bias,
                                             const float* __restrict__ ws_bias,
                                             unsigned char* __restrict__ encF8,
                                             float* __restrict__ logT) {
    __shared__ unsigned short Wt[128 * 128];
    __shared__ unsigned short Ht[32 * 128];
    __shared__ unsigned short Et[32 * 128];

    const int tid = threadIdx.x;
    const int lane = tid & 63, w = tid >> 6;
    const int c = lane & 15, g = lane >> 4;
    const int wd = w >> 1, wt = w & 1;
    const int t0 = blockIdx.x * 32;

    f32x4 acc[4] = {};
    for (int ks = 0; ks < 8; ++ks) {
        #pragma unroll
        for (int it = 0; it < 8; ++it) {
            int m = it * 256 + tid;
            int row = m >> 4, gc = m & 15;
            short8 v = *(const short8*)(we0b + row * 1024 + ks * 128 + gc * 8);
            *(short8*)&Wt[row * 128 + ((gc ^ (row & 7)) * 8)] = v;
        }
        #pragma unroll
        for (int it = 0; it < 2; ++it) {
            int m = it * 256 + tid;
            int row = m >> 4, gc = m & 15;
            const float* hp = h0 + (size_t)(t0 + row) * 1024 + ks * 128 + gc * 8;
            fv4 v0 = *(const fv4*)hp;
            fv4 v1 = *(const fv4*)(hp + 4);
            short8 ov;
            ov[0] = (short)f2bf(v0.x); ov[1] = (short)f2bf(v0.y);
            ov[2] = (short)f2bf(v0.z); ov[3] = (short)f2bf(v0.w);
            ov[4] = (short)f2bf(v1.x); ov[5] = (short)f2bf(v1.y);
            ov[6] = (short)f2bf(v1.z); ov[7] = (short)f2bf(v1.w);
            *(short8*)&Ht[row * 128 + ((gc ^ (row & 7)) * 8)] = ov;
        }
        __syncthreads();
        #pragma unroll
        for (int s = 0; s < 4; ++s) {
            int gk = s * 4 + g;
            int brow = wt * 16 + c;
            short8 b = *(const short8*)&Ht[brow * 128 + ((gk ^ (brow & 7)) * 8)];
            #pragma unroll
            for (int jf = 0; jf < 4; ++jf) {
                int j = wd * 64 + jf * 16 + c;
                short8 a = *(const short8*)&Wt[j * 128 + ((gk ^ (j & 7)) * 8)];
                acc[jf] = __builtin_amdgcn_mfma_f32_16x16x32_bf16(a, b, acc[jf], 0, 0, 0);
            }
        }
        __syncthreads();
    }
    const int tile = blockIdx.x * 2 + wt;
    const int erow = wt * 16 + c;
    #pragma unroll
    for (int f = 0; f < 4; ++f) {
        int d0 = wd * 64 + f * 16 + 4 * g;
        fv4 bi = *(const fv4*)(we0_bias + d0);
        float v0 = acc[f][0] + bi.x, v1 = acc[f][1] + bi.y;
        float v2 = acc[f][2] + bi.z, v3 = acc[f][3] + bi.w;
        // fp8 pack -> encF8
        int pk = __builtin_amdgcn_cvt_pk_fp8_f32(v0, v1, 0, false);
        pk = __builtin_amdgcn_cvt_pk_fp8_f32(v2, v3, pk, true);
        int s = wd * 2 + (f >> 1);
        int chunk = (f & 1) * 2 + (g >> 1);
        int e = (g & 1) * 4;
        *(unsigned*)(encF8 + (size_t)tile * 2048 + (chunk * 16 + c) * 32 + s * 8 + e) = (unsigned)pk;
        // bf16 -> LDS Et for fused logits
        us4 o;
        o.x = f2bf(v0); o.y = f2bf(v1); o.z = f2bf(v2); o.w = f2bf(v3);
        int cg = d0 >> 3, off = d0 & 7;
        *(us4*)&Et[erow * 128 + ((cg ^ (erow & 7)) * 8) + off] = o;
    }
    __syncthreads();

    short8 al[4][4];
    #pragma unroll
    for (int jf = 0; jf < 4; ++jf)
        #pragma unroll
        for (int s = 0; s < 4; ++s)
            al[jf][s] = *(const short8*)(wsb + (wd * 64 + jf * 16 + c) * 128 + s * 32 + g * 8);
    short8 bl[4];
    #pragma unroll
    for (int s = 0; s < 4; ++s) {
        int cg2 = s * 4 + g;
        bl[s] = *(const short8*)&Et[erow * 128 + ((cg2 ^ (erow & 7)) * 8)];
    }
    f32x4 acc2[4] = {};
    #pragma unroll
    for (int s = 0; s < 4; ++s)
        #pragma unroll
        for (int jf = 0; jf < 4; ++jf)
            acc2[jf] = __builtin_amdgcn_mfma_f32_16x16x32_bf16(al[jf][s], bl[s], acc2[jf], 0, 0, 0);
    const int tokc = t0 + wt * 16 + c;
    #pragma unroll
    for (int jf = 0; jf < 4; ++jf) {
        int m0 = wd * 64 + jf * 16 + 4 * g;
        fv4 bs = *(const fv4*)(ws_bias + m0);
        logT[(size_t)(m0 + 0) * N_TOK + tokc] = acc2[jf][0] + bs.x;
        logT[(size_t)(m0 + 1) * N_TOK + tokc] = acc2[jf][1] + bs.y;
        logT[(size_t)(m0 + 2) * N_TOK + tokc] = acc2[jf][2] + bs.z;
        logT[(size_t)(m0 + 3) * N_TOK + tokc] = acc2[jf][3] + bs.w;
    }
}

// ---------------- gate = softmax over axis 0, per column m (bf16, tiled) ----------------
__global__ __launch_bounds__(1024) void k_softmax0(const float* __restrict__ logT,
                                                   unsigned short* __restrict__ gateT) {
    __shared__ float red[32];
    const int m = blockIdx.x;
    const int tid = threadIdx.x;
    const int lane = tid & 63, wv = tid >> 6;   // 16 waves
    const float* row = logT + (size_t)m * N_TOK;

    fv4 v[4];
    float vmax = -3.0e38f;
    #pragma unroll
    for (int it = 0; it < 4; ++it) {
        v[it] = *(const fv4*)(row + it * 4096 + tid * 4);
        vmax = fmaxf(vmax, fmaxf(fmaxf(v[it].x, v[it].y), fmaxf(v[it].z, v[it].w)));
    }
    #pragma unroll
    for (int o = 32; o > 0; o >>= 1) vmax = fmaxf(vmax, __shfl_xor(vmax, o));
    if (lane == 0) red[wv] = vmax;
    __syncthreads();
    float bmax = -3.0e38f;
    #pragma unroll
    for (int k = 0; k < 16; ++k) bmax = fmaxf(bmax, red[k]);

    float s = 0.f;
    #pragma unroll
    for (int it = 0; it < 4; ++it) {
        v[it].x = __expf(v[it].x - bmax); v[it].y = __expf(v[it].y - bmax);
        v[it].z = __expf(v[it].z - bmax); v[it].w = __expf(v[it].w - bmax);
        s += v[it].x + v[it].y + v[it].z + v[it].w;
    }
    #pragma unroll
    for (int o = 32; o > 0; o >>= 1) s += __shfl_xor(s, o);
    if (lane == 0) red[16 + wv] = s;
    __syncthreads();
    float bs = 0.f;
    #pragma unroll
    for (int k = 0; k < 16; ++k) bs += red[16 + k];
    const float inv = 1.f / bs;

    const int q  = m >> 5;
    const int w8 = ((m >> 4) & 1) * 4 + (m & 3);
    const int gl = ((m & 15) >> 2) * 16;
    #pragma unroll
    for (int it = 0; it < 4; ++it) {
        int t = it * 4096 + tid * 4;
        float pv[4] = { v[it].x * inv, v[it].y * inv, v[it].z * inv, v[it].w * inv };
        #pragma unroll
        for (int k = 0; k < 4; ++k) {
            int tok = t + k;
            gateT[(size_t)(tok >> 4) * 2048 + q * 512 + (gl + (tok & 15)) * 8 + w8] = f2bf(pv[k]);
        }
    }
}

// ---------------- k_mix: fp8 reg panel, 3 waves/SIMD (proven best, untouched) ----------------
__global__ __launch_bounds__(256)
__attribute__((amdgpu_waves_per_eu(3, 3)))
void k_mix(const unsigned char* __restrict__ wmf8,
           const unsigned char* __restrict__ encF8,
           const unsigned short* __restrict__ gateT,
           const float* __restrict__ wm_bias,
           unsigned short* __restrict__ mixT) {
    const int bid = blockIdx.x;
    const int i = bid & 127, part = bid >> 7;
    const int tid = threadIdx.x;
    const int lane = tid & 63, w = tid >> 6;
    const int c = lane & 15, g = lane >> 4;

    const unsigned char* wmi = wmf8 + (size_t)i * 16384;
    uint2 a[8][4];
    #pragma unroll
    for (int jf = 0; jf < 8; ++jf)
        #pragma unroll
        for (int s = 0; s < 4; ++s) {
            a[jf][s] = *(const uint2*)(wmi + (jf * 16 + c) * 128 + s * 32 + g * 8);
            asm volatile("" : "+v"(a[jf][s]));
        }
    f32x4 bias4[8];
    #pragma unroll
    for (int f = 0; f < 8; ++f) {
        bias4[f] = *(const f32x4*)(wm_bias + i * 128 + f * 16 + 4 * g);
        asm volatile("" : "+v"(bias4[f]));
    }

    const int start = part * 42 + (part < 4 ? part : 4);
    const int cnt = 42 + (part < 4 ? 1 : 0);
    const int si = i >> 5, ch = (i & 31) >> 3, ei = i & 7;

    const unsigned char* encB = encF8 + (size_t)(start * 4 + w) * 2048 + lane * 32;
    const unsigned* gateB = (const unsigned*)(gateT + (size_t)(start * 4 + w) * 2048) + lane * 4;
    unsigned short* mixB = mixT + (size_t)(start * 4 + w) * 2048 + si * 512 + (ch * 16 + lane) * 8 + ei;

    // prologue: enc frag for t=0
    uint4 q0 = *(const uint4*)(encB);
    uint4 q1 = *(const uint4*)(encB + 16);

    #pragma unroll 1
    for (int t = 0; t < cnt; ++t) {
        // gate loads for CURRENT tile: latency hides under the MFMA block
        const unsigned* gp = gateB + (size_t)t * 4096;
        uint4 G0 = *(const uint4*)(gp);
        uint4 G1 = *(const uint4*)(gp + 256);
        uint4 G2 = *(const uint4*)(gp + 512);
        uint4 G3 = *(const uint4*)(gp + 768);

        long b0 = __builtin_bit_cast(long, (uint2){q0.x, q0.y});
        long b1 = __builtin_bit_cast(long, (uint2){q0.z, q0.w});
        long b2 = __builtin_bit_cast(long, (uint2){q1.x, q1.y});
        long b3 = __builtin_bit_cast(long, (uint2){q1.z, q1.w});

        __builtin_amdgcn_s_setprio(1);
        f32x4 acc[8];
        #pragma unroll
        for (int jf = 0; jf < 8; ++jf)
            acc[jf] = __builtin_amdgcn_mfma_f32_16x16x32_fp8_fp8(
                __builtin_bit_cast(long, a[jf][0]), b0, bias4[jf], 0, 0, 0);
        #pragma unroll
        for (int jf = 0; jf < 8; ++jf)
            acc[jf] = __builtin_amdgcn_mfma_f32_16x16x32_fp8_fp8(
                __builtin_bit_cast(long, a[jf][1]), b1, acc[jf], 0, 0, 0);
        #pragma unroll
        for (int jf = 0; jf < 8; ++jf)
            acc[jf] = __builtin_amdgcn_mfma_f32_16x16x32_fp8_fp8(
                __builtin_bit_cast(long, a[jf][2]), b2, acc[jf], 0, 0, 0);
        #pragma unroll
        for (int jf = 0; jf < 8; ++jf)
            acc[jf] = __builtin_amdgcn_mfma_f32_16x16x32_fp8_fp8(
                __builtin_bit_cast(long, a[jf][3]), b3, acc[jf], 0, 0, 0);
        __builtin_amdgcn_s_setprio(0);

        // prefetch next tile's enc frag (consumed next iteration)
        {
            const int tn = (t + 1 < cnt) ? t + 1 : t;
            const unsigned char* ebn = encB + (size_t)tn * 8192;
            q0 = *(const uint4*)(ebn);
            q1 = *(const uint4*)(ebn + 16);
        }

        float p0 = 0.f, p1 = 0.f, p2 = 0.f, p3 = 0.f;
        #define EPI(F, GA, GB) {                                        \
            p0 += fmaxf(acc[F][0], 0.f) * bf2f_lo(GA);                  \
            p1 += fmaxf(acc[F][1], 0.f) * bf2f_hi(GA);                  \
            p2 += fmaxf(acc[F][2], 0.f) * bf2f_lo(GB);                  \
            p3 += fmaxf(acc[F][3], 0.f) * bf2f_hi(GB);                  \
        }
        EPI(0, G0.x, G0.y) EPI(1, G0.z, G0.w)
        EPI(2, G1.x, G1.y) EPI(3, G1.z, G1.w)
        EPI(4, G2.x, G2.y) EPI(5, G2.z, G2.w)
        EPI(6, G3.x, G3.y) EPI(7, G3.z, G3.w)
        #undef EPI
        float p = (p0 + p1) + (p2 + p3);
        p += __shfl_xor(p, 16);
        p += __shfl_xor(p, 32);
        if (lane < 16) *(mixB + (size_t)t * 8192) = f2bf(p);
    }
}

// ---------------- out = relu(mixed @ we1^T + b1 + h0) ----------------
// v18: LDS we1 panel (32KB, k_enc-style swizzle) -> ~135 VGPR -> 3 waves/SIMD.
// grid 768 = 8 eb x 96 tg; tg covers 2-3 groups of 4 tiles (64 tokens each).
__global__ __launch_bounds__(256)
__attribute__((amdgpu_waves_per_eu(3, 3)))
void k_dec(const unsigned short* __restrict__ we1b,
           const unsigned short* __restrict__ mixT,
           const float* __restrict__ we1_bias,
           const float* __restrict__ h0,
           float* __restrict__ out) {
    __shared__ unsigned short Pt[128 * 128];   // we1 eb-panel, swizzled (32 KB)

    const int bid = blockIdx.x;
    const int eb = bid & 7, tg = bid >> 3;     // tg in [0,96)
    const int e0 = eb * 128;
    const int tid = threadIdx.x;
    const int lane = tid & 63, w = tid >> 6;
    const int c = lane & 15, g = lane >> 4;

    // stage we1 rows e0..e0+127 into LDS, XOR-swizzled (k_enc Wt pattern)
    #pragma unroll
    for (int it = 0; it < 8; ++it) {
        int m = it * 256 + tid;
        int row = m >> 4, gc = m & 15;
        short8 v = *(const short8*)(we1b + (size_t)(e0 + row) * 128 + gc * 8);
        *(short8*)&Pt[row * 128 + ((gc ^ (row & 7)) * 8)] = v;
    }
    __syncthreads();

    fv4 bi[8];
    #pragma unroll
    for (int f = 0; f < 8; ++f)
        bi[f] = *(const fv4*)(we1_bias + e0 + f * 16 + 4 * g);

    // 256 groups of 4 tiles over 96 tg: first 64 tg take 3 groups, rest 2.
    const int start = tg * 2 + (tg < 64 ? tg : 64);
    const int cnt = 2 + (tg < 64 ? 1 : 0);

    #pragma unroll 1
    for (int t = 0; t < cnt; ++t) {
        const int tile = (start + t) * 4 + w;
        const int tokr = tile * 16 + c;
        // issue h0 loads first (HBM, longest latency)
        fv4 h[8];
        #pragma unroll
        for (int f = 0; f < 8; ++f)
            h[f] = *(const fv4*)(h0 + (size_t)tokr * 1024 + e0 + f * 16 + 4 * g);
        const unsigned short* mp = mixT + (size_t)tile * 2048 + lane * 8;
        short8 b[4];
        #pragma unroll
        for (int s = 0; s < 4; ++s)
            b[s] = *(const short8*)(mp + s * 512);

        f32x4 acc[8] = {};
        #pragma unroll
        for (int s = 0; s < 4; ++s) {
            int gk = s * 4 + g;
            #pragma unroll
            for (int jf = 0; jf < 8; ++jf) {
                int row = jf * 16 + c;
                short8 av = *(const short8*)&Pt[row * 128 + ((gk ^ (row & 7)) * 8)];
                acc[jf] = __builtin_amdgcn_mfma_f32_16x16x32_bf16(av, b[s], acc[jf], 0, 0, 0);
            }
        }

        #pragma unroll
        for (int f = 0; f < 8; ++f) {
            fv4 o;
            o.x = fmaxf(acc[f][0] + bi[f].x + h[f].x, 0.f);
            o.y = fmaxf(acc[f][1] + bi[f].y + h[f].y, 0.f);
            o.z = fmaxf(acc[f][2] + bi[f].z + h[f].z, 0.f);
            o.w = fmaxf(acc[f][3] + bi[f].w + h[f].w, 0.f);
            *(fv4*)(out + (size_t)tokr * 1024 + e0 + f * 16 + 4 * g) = o;
        }
    }
}

extern "C" void kernel_launch(void* const* d_in, const int* in_sizes, int n_in,
                              void* d_out, int out_size, void* d_ws, size_t ws_size,
                              hipStream_t stream) {
    const float* h0    = (const float*)d_in[0];
    const float* we0_w = (const float*)d_in[1];
    const float* we0_b = (const float*)d_in[2];
    const float* ws_w  = (const float*)d_in[3];
    const float* ws_b  = (const float*)d_in[4];
    const float* wm_w  = (const float*)d_in[5];
    const float* wm_b  = (const float*)d_in[6];
    const float* we1_w = (const float*)d_in[7];
    const float* we1_b = (const float*)d_in[8];
    float* out = (float*)d_out;

    unsigned*       wmf8  = (unsigned*)d_ws;             // 2 MB fp8 (row-major)
    unsigned short* we0b  = (unsigned short*)(wmf8 + 524288); // 128*1024 bf16
    unsigned short* we1b  = we0b + 131072;               // 1024*128 bf16
    unsigned short* wsb   = we1b + 131072;               // 128*128 bf16
    unsigned char*  encF8 = (unsigned char*)(wsb + 16384);     // 2 MB fp8 (tiled)
    float*          logT  = (float*)(encF8 + 2097152);   // [128][16384] f32
    unsigned short* gateT = (unsigned short*)(logT + 2097152); // 4 MB bf16 (tiled)
    unsigned short* mixT  = gateT + 2097152;             // 4 MB bf16 (tiled)

    k_convert_all<<<640, 256, 0, stream>>>(wm_w, we0_w, we1_w, ws_w, wmf8, we0b);
    k_enc<<<512, 256, 0, stream>>>(h0, we0b, wsb, we0_b, ws_b, encF8, logT);
    k_softmax0<<<128, 1024, 0, stream>>>(logT, gateT);
    k_mix<<<768, 256, 0, stream>>>((const unsigned char*)wmf8, encF8, gateT, wm_b, mixT);
    k_dec<<<768, 256, 0, stream>>>(we1b, mixT, we1_b, h0, out);
}

// Round 18
// 157.258 us; speedup vs baseline: 1.0803x; 1.0803x over previous
//
#include <hip/hip_runtime.h>

// DomDepResidualLayer: out = relu(h0 + (mixed @ we1^T + b1))
//   enc   = h0 @ we0^T + b0                         [16384,128]
//   acts  = relu(einsum('nd,mkd->mnk', enc, wm)+bm) (never materialized)
//   gate  = softmax(enc @ ws^T + bs, axis=0)        [16384,128]
//   mixed[n,i] = sum_j acts[i,n,j]*gate[n,j]        [16384,128]
// v19 = exact v17 (proven best, 158.2us, reproduced 3x):
//   k_mix: fp8 e4m3 reg panel (64 VGPR) + bias pinned, 3 waves/SIMD,
//   grid 768 (module-fast decode), gate bf16 tiled, enc fp8 tiled,
//   gate loads before MFMA block, enc prefetch after.
//   k_enc fused logits; k_dec 512 blocks, register we1 panel (v18's LDS
//   variant measured -11.7us and is reverted).
// Ledger (all measured vs this config): scheduling variants (v5-v10,v15)
// neutral; occupancy restructures (v12,v13) L2-thrash; f32 gate (v16),
// pk_fma epilogue (v16), cvt_pk asm + k_dec regrid (v14), LDS k_dec (v18)
// all negative. This is the empirical fixed point of this design.

#define N_TOK   16384
#define EMB     1024
#define MDIM    128

typedef __attribute__((ext_vector_type(8))) short   short8;   // 8 bf16 = 1 bf16 MFMA frag
typedef __attribute__((ext_vector_type(4))) float   f32x4;
typedef __attribute__((ext_vector_type(4))) float   fv4;
typedef __attribute__((ext_vector_type(4))) unsigned short us4;

static __device__ __forceinline__ unsigned short f2bf(float f) {
    union { float f; unsigned u; } v; v.f = f;
    unsigned r = v.u + 0x7FFFu + ((v.u >> 16) & 1u);   // RNE
    return (unsigned short)(r >> 16);
}
static __device__ __forceinline__ float bf2f_lo(unsigned u) {
    union { unsigned u; float f; } v; v.u = u << 16; return v.f;
}
static __device__ __forceinline__ float bf2f_hi(unsigned u) {
    union { unsigned u; float f; } v; v.u = u & 0xffff0000u; return v.f;
}

// ---------------- fused weight conversion: wm -> fp8, we0/we1/ws -> bf16 ----------------
__global__ void k_convert_all(const float* __restrict__ wm_w,
                              const float* __restrict__ we0_w,
                              const float* __restrict__ we1_w,
                              const float* __restrict__ ws_w,
                              unsigned* __restrict__ wmf8,
                              unsigned short* __restrict__ bf16dst) {
    const int N = 524288 + 36864;
    for (int i = blockIdx.x * blockDim.x + threadIdx.x; i < N;
         i += gridDim.x * blockDim.x) {
        if (i < 524288) {                       // wm -> fp8 e4m3, 4 vals per u32
            fv4 v = *(const fv4*)(wm_w + (size_t)i * 4);
            int pk = __builtin_amdgcn_cvt_pk_fp8_f32(v.x, v.y, 0, false);
            pk = __builtin_amdgcn_cvt_pk_fp8_f32(v.z, v.w, pk, true);
            wmf8[i] = (unsigned)pk;
        } else {                                // we0|we1|ws -> bf16
            int j = i - 524288;
            const float* src;
            if (j < 32768)      src = we0_w + (size_t)j * 4;
            else if (j < 65536) src = we1_w + (size_t)(j - 32768) * 4;
            else                src = ws_w  + (size_t)(j - 65536) * 4;
            fv4 v = *(const fv4*)src;
            us4 o;
            o.x = f2bf(v.x); o.y = f2bf(v.y); o.z = f2bf(v.z); o.w = f2bf(v.w);
            *(us4*)(bf16dst + (size_t)j * 4) = o;
        }
    }
}

// encF8 fp8 tile layout (2048 B per 16-tok tile), per-lane-contiguous:
//   byte(tok, d) = tile*2048 + (((d&31)>>3)*16 + tok)*32 + (d>>5)*8 + (d&7)
// gateT bf16 tile layout (2048 bf16 per tile):
//   elem(tok, j=f*16+4g+rr) = tile*2048 + (f>>1)*512 + (g*16 + (tok&15))*8 + (f&1)*4 + rr

// ---------------- enc = h0 @ we0^T + b0 (fp8 out), fused logits = enc @ ws^T + bs ----------------
__global__ __launch_bounds__(256) void k_enc(const float* __restrict__ h0,
                                             const unsigned short* __restrict__ we0b,
                                             const unsigned short* __restrict__ wsb,
                                             const float* __restrict__ we0_bias,
                                             const float* __restrict__ ws_bias,
                                             unsigned char* __restrict__ encF8,
                                             float* __restrict__ logT) {
    __shared__ unsigned short Wt[128 * 128];
    __shared__ unsigned short Ht[32 * 128];
    __shared__ unsigned short Et[32 * 128];

    const int tid = threadIdx.x;
    const int lane = tid & 63, w = tid >> 6;
    const int c = lane & 15, g = lane >> 4;
    const int wd = w >> 1, wt = w & 1;
    const int t0 = blockIdx.x * 32;

    f32x4 acc[4] = {};
    for (int ks = 0; ks < 8; ++ks) {
        #pragma unroll
        for (int it = 0; it < 8; ++it) {
            int m = it * 256 + tid;
            int row = m >> 4, gc = m & 15;
            short8 v = *(const short8*)(we0b + row * 1024 + ks * 128 + gc * 8);
            *(short8*)&Wt[row * 128 + ((gc ^ (row & 7)) * 8)] = v;
        }
        #pragma unroll
        for (int it = 0; it < 2; ++it) {
            int m = it * 256 + tid;
            int row = m >> 4, gc = m & 15;
            const float* hp = h0 + (size_t)(t0 + row) * 1024 + ks * 128 + gc * 8;
            fv4 v0 = *(const fv4*)hp;
            fv4 v1 = *(const fv4*)(hp + 4);
            short8 ov;
            ov[0] = (short)f2bf(v0.x); ov[1] = (short)f2bf(v0.y);
            ov[2] = (short)f2bf(v0.z); ov[3] = (short)f2bf(v0.w);
            ov[4] = (short)f2bf(v1.x); ov[5] = (short)f2bf(v1.y);
            ov[6] = (short)f2bf(v1.z); ov[7] = (short)f2bf(v1.w);
            *(short8*)&Ht[row * 128 + ((gc ^ (row & 7)) * 8)] = ov;
        }
        __syncthreads();
        #pragma unroll
        for (int s = 0; s < 4; ++s) {
            int gk = s * 4 + g;
            int brow = wt * 16 + c;
            short8 b = *(const short8*)&Ht[brow * 128 + ((gk ^ (brow & 7)) * 8)];
            #pragma unroll
            for (int jf = 0; jf < 4; ++jf) {
                int j = wd * 64 + jf * 16 + c;
                short8 a = *(const short8*)&Wt[j * 128 + ((gk ^ (j & 7)) * 8)];
                acc[jf] = __builtin_amdgcn_mfma_f32_16x16x32_bf16(a, b, acc[jf], 0, 0, 0);
            }
        }
        __syncthreads();
    }
    const int tile = blockIdx.x * 2 + wt;
    const int erow = wt * 16 + c;
    #pragma unroll
    for (int f = 0; f < 4; ++f) {
        int d0 = wd * 64 + f * 16 + 4 * g;
        fv4 bi = *(const fv4*)(we0_bias + d0);
        float v0 = acc[f][0] + bi.x, v1 = acc[f][1] + bi.y;
        float v2 = acc[f][2] + bi.z, v3 = acc[f][3] + bi.w;
        // fp8 pack -> encF8
        int pk = __builtin_amdgcn_cvt_pk_fp8_f32(v0, v1, 0, false);
        pk = __builtin_amdgcn_cvt_pk_fp8_f32(v2, v3, pk, true);
        int s = wd * 2 + (f >> 1);
        int chunk = (f & 1) * 2 + (g >> 1);
        int e = (g & 1) * 4;
        *(unsigned*)(encF8 + (size_t)tile * 2048 + (chunk * 16 + c) * 32 + s * 8 + e) = (unsigned)pk;
        // bf16 -> LDS Et for fused logits
        us4 o;
        o.x = f2bf(v0); o.y = f2bf(v1); o.z = f2bf(v2); o.w = f2bf(v3);
        int cg = d0 >> 3, off = d0 & 7;
        *(us4*)&Et[erow * 128 + ((cg ^ (erow & 7)) * 8) + off] = o;
    }
    __syncthreads();

    short8 al[4][4];
    #pragma unroll
    for (int jf = 0; jf < 4; ++jf)
        #pragma unroll
        for (int s = 0; s < 4; ++s)
            al[jf][s] = *(const short8*)(wsb + (wd * 64 + jf * 16 + c) * 128 + s * 32 + g * 8);
    short8 bl[4];
    #pragma unroll
    for (int s = 0; s < 4; ++s) {
        int cg2 = s * 4 + g;
        bl[s] = *(const short8*)&Et[erow * 128 + ((cg2 ^ (erow & 7)) * 8)];
    }
    f32x4 acc2[4] = {};
    #pragma unroll
    for (int s = 0; s < 4; ++s)
        #pragma unroll
        for (int jf = 0; jf < 4; ++jf)
            acc2[jf] = __builtin_amdgcn_mfma_f32_16x16x32_bf16(al[jf][s], bl[s], acc2[jf], 0, 0, 0);
    const int tokc = t0 + wt * 16 + c;
    #pragma unroll
    for (int jf = 0; jf < 4; ++jf) {
        int m0 = wd * 64 + jf * 16 + 4 * g;
        fv4 bs = *(const fv4*)(ws_bias + m0);
        logT[(size_t)(m0 + 0) * N_TOK + tokc] = acc2[jf][0] + bs.x;
        logT[(size_t)(m0 + 1) * N_TOK + tokc] = acc2[jf][1] + bs.y;
        logT[(size_t)(m0 + 2) * N_TOK + tokc] = acc2[jf][2] + bs.z;
        logT[(size_t)(m0 + 3) * N_TOK + tokc] = acc2[jf][3] + bs.w;
    }
}

// ---------------- gate = softmax over axis 0, per column m (bf16, tiled) ----------------
__global__ __launch_bounds__(1024) void k_softmax0(const float* __restrict__ logT,
                                                   unsigned short* __restrict__ gateT) {
    __shared__ float red[32];
    const int m = blockIdx.x;
    const int tid = threadIdx.x;
    const int lane = tid & 63, wv = tid >> 6;   // 16 waves
    const float* row = logT + (size_t)m * N_TOK;

    fv4 v[4];
    float vmax = -3.0e38f;
    #pragma unroll
    for (int it = 0; it < 4; ++it) {
        v[it] = *(const fv4*)(row + it * 4096 + tid * 4);
        vmax = fmaxf(vmax, fmaxf(fmaxf(v[it].x, v[it].y), fmaxf(v[it].z, v[it].w)));
    }
    #pragma unroll
    for (int o = 32; o > 0; o >>= 1) vmax = fmaxf(vmax, __shfl_xor(vmax, o));
    if (lane == 0) red[wv] = vmax;
    __syncthreads();
    float bmax = -3.0e38f;
    #pragma unroll
    for (int k = 0; k < 16; ++k) bmax = fmaxf(bmax, red[k]);

    float s = 0.f;
    #pragma unroll
    for (int it = 0; it < 4; ++it) {
        v[it].x = __expf(v[it].x - bmax); v[it].y = __expf(v[it].y - bmax);
        v[it].z = __expf(v[it].z - bmax); v[it].w = __expf(v[it].w - bmax);
        s += v[it].x + v[it].y + v[it].z + v[it].w;
    }
    #pragma unroll
    for (int o = 32; o > 0; o >>= 1) s += __shfl_xor(s, o);
    if (lane == 0) red[16 + wv] = s;
    __syncthreads();
    float bs = 0.f;
    #pragma unroll
    for (int k = 0; k < 16; ++k) bs += red[16 + k];
    const float inv = 1.f / bs;

    const int q  = m >> 5;
    const int w8 = ((m >> 4) & 1) * 4 + (m & 3);
    const int gl = ((m & 15) >> 2) * 16;
    #pragma unroll
    for (int it = 0; it < 4; ++it) {
        int t = it * 4096 + tid * 4;
        float pv[4] = { v[it].x * inv, v[it].y * inv, v[it].z * inv, v[it].w * inv };
        #pragma unroll
        for (int k = 0; k < 4; ++k) {
            int tok = t + k;
            gateT[(size_t)(tok >> 4) * 2048 + q * 512 + (gl + (tok & 15)) * 8 + w8] = f2bf(pv[k]);
        }
    }
}

// ---------------- k_mix: fp8 reg panel, 3 waves/SIMD (proven best) ----------------
// grid 768: i = bid&127 (module), part = bid>>7 in [0,6). Part p covers
// tile-groups [p*42+min(p,4), +42+(p<4)). 4 waves/block, wave w takes
// tile = group*4 + w. Panel 64 VGPR fp8 pinned; G issued before MFMA block;
// enc prefetched after MFMA block.
__global__ __launch_bounds__(256)
__attribute__((amdgpu_waves_per_eu(3, 3)))
void k_mix(const unsigned char* __restrict__ wmf8,
           const unsigned char* __restrict__ encF8,
           const unsigned short* __restrict__ gateT,
           const float* __restrict__ wm_bias,
           unsigned short* __restrict__ mixT) {
    const int bid = blockIdx.x;
    const int i = bid & 127, part = bid >> 7;
    const int tid = threadIdx.x;
    const int lane = tid & 63, w = tid >> 6;
    const int c = lane & 15, g = lane >> 4;

    const unsigned char* wmi = wmf8 + (size_t)i * 16384;
    uint2 a[8][4];
    #pragma unroll
    for (int jf = 0; jf < 8; ++jf)
        #pragma unroll
        for (int s = 0; s < 4; ++s) {
            a[jf][s] = *(const uint2*)(wmi + (jf * 16 + c) * 128 + s * 32 + g * 8);
            asm volatile("" : "+v"(a[jf][s]));
        }
    f32x4 bias4[8];
    #pragma unroll
    for (int f = 0; f < 8; ++f) {
        bias4[f] = *(const f32x4*)(wm_bias + i * 128 + f * 16 + 4 * g);
        asm volatile("" : "+v"(bias4[f]));
    }

    const int start = part * 42 + (part < 4 ? part : 4);
    const int cnt = 42 + (part < 4 ? 1 : 0);
    const int si = i >> 5, ch = (i & 31) >> 3, ei = i & 7;

    const unsigned char* encB = encF8 + (size_t)(start * 4 + w) * 2048 + lane * 32;
    const unsigned* gateB = (const unsigned*)(gateT + (size_t)(start * 4 + w) * 2048) + lane * 4;
    unsigned short* mixB = mixT + (size_t)(start * 4 + w) * 2048 + si * 512 + (ch * 16 + lane) * 8 + ei;

    // prologue: enc frag for t=0
    uint4 q0 = *(const uint4*)(encB);
    uint4 q1 = *(const uint4*)(encB + 16);

    #pragma unroll 1
    for (int t = 0; t < cnt; ++t) {
        // gate loads for CURRENT tile: latency hides under the MFMA block
        const unsigned* gp = gateB + (size_t)t * 4096;
        uint4 G0 = *(const uint4*)(gp);
        uint4 G1 = *(const uint4*)(gp + 256);
        uint4 G2 = *(const uint4*)(gp + 512);
        uint4 G3 = *(const uint4*)(gp + 768);

        long b0 = __builtin_bit_cast(long, (uint2){q0.x, q0.y});
        long b1 = __builtin_bit_cast(long, (uint2){q0.z, q0.w});
        long b2 = __builtin_bit_cast(long, (uint2){q1.x, q1.y});
        long b3 = __builtin_bit_cast(long, (uint2){q1.z, q1.w});

        __builtin_amdgcn_s_setprio(1);
        f32x4 acc[8];
        #pragma unroll
        for (int jf = 0; jf < 8; ++jf)
            acc[jf] = __builtin_amdgcn_mfma_f32_16x16x32_fp8_fp8(
                __builtin_bit_cast(long, a[jf][0]), b0, bias4[jf], 0, 0, 0);
        #pragma unroll
        for (int jf = 0; jf < 8; ++jf)
            acc[jf] = __builtin_amdgcn_mfma_f32_16x16x32_fp8_fp8(
                __builtin_bit_cast(long, a[jf][1]), b1, acc[jf], 0, 0, 0);
        #pragma unroll
        for (int jf = 0; jf < 8; ++jf)
            acc[jf] = __builtin_amdgcn_mfma_f32_16x16x32_fp8_fp8(
                __builtin_bit_cast(long, a[jf][2]), b2, acc[jf], 0, 0, 0);
        #pragma unroll
        for (int jf = 0; jf < 8; ++jf)
            acc[jf] = __builtin_amdgcn_mfma_f32_16x16x32_fp8_fp8(
                __builtin_bit_cast(long, a[jf][3]), b3, acc[jf], 0, 0, 0);
        __builtin_amdgcn_s_setprio(0);

        // prefetch next tile's enc frag (consumed next iteration)
        {
            const int tn = (t + 1 < cnt) ? t + 1 : t;
            const unsigned char* ebn = encB + (size_t)tn * 8192;
            q0 = *(const uint4*)(ebn);
            q1 = *(const uint4*)(ebn + 16);
        }

        float p0 = 0.f, p1 = 0.f, p2 = 0.f, p3 = 0.f;
        #define EPI(F, GA, GB) {                                        \
            p0 += fmaxf(acc[F][0], 0.f) * bf2f_lo(GA);                  \
            p1 += fmaxf(acc[F][1], 0.f) * bf2f_hi(GA);                  \
            p2 += fmaxf(acc[F][2], 0.f) * bf2f_lo(GB);                  \
            p3 += fmaxf(acc[F][3], 0.f) * bf2f_hi(GB);                  \
        }
        EPI(0, G0.x, G0.y) EPI(1, G0.z, G0.w)
        EPI(2, G1.x, G1.y) EPI(3, G1.z, G1.w)
        EPI(4, G2.x, G2.y) EPI(5, G2.z, G2.w)
        EPI(6, G3.x, G3.y) EPI(7, G3.z, G3.w)
        #undef EPI
        float p = (p0 + p1) + (p2 + p3);
        p += __shfl_xor(p, 16);
        p += __shfl_xor(p, 32);
        if (lane < 16) *(mixB + (size_t)t * 8192) = f2bf(p);
    }
}

// ---------------- out = relu(mixed @ we1^T + b1 + h0) ----------------
// grid 512 = 8 eb x 64 tg (256 tokens each, t<4).
__global__ __launch_bounds__(256)
__attribute__((amdgpu_waves_per_eu(2, 2)))
void k_dec(const unsigned short* __restrict__ we1b,
           const unsigned short* __restrict__ mixT,
           const float* __restrict__ we1_bias,
           const float* __restrict__ h0,
           float* __restrict__ out) {
    const int bid = blockIdx.x;
    const int eb = bid & 7, tg = bid >> 3;
    const int e0 = eb * 128;
    const int tid = threadIdx.x;
    const int lane = tid & 63, w = tid >> 6;
    const int c = lane & 15, g = lane >> 4;

    short8 a[8][4];
    #pragma unroll
    for (int jf = 0; jf < 8; ++jf)
        #pragma unroll
        for (int s = 0; s < 4; ++s) {
            a[jf][s] = *(const short8*)(we1b + (size_t)(e0 + jf * 16 + c) * 128 + s * 32 + g * 8);
            asm volatile("" : "+v"(a[jf][s]));
        }
    fv4 bi[8];
    #pragma unroll
    for (int f = 0; f < 8; ++f)
        bi[f] = *(const fv4*)(we1_bias + e0 + f * 16 + 4 * g);

    #pragma unroll 1
    for (int t = 0; t < 4; ++t) {
        const int tokr = tg * 256 + t * 64 + w * 16 + c;
        const int tile = tg * 16 + t * 4 + w;
        fv4 h[8];
        #pragma unroll
        for (int f = 0; f < 8; ++f)
            h[f] = *(const fv4*)(h0 + (size_t)tokr * 1024 + e0 + f * 16 + 4 * g);
        const unsigned short* mp = mixT + (size_t)tile * 2048 + lane * 8;
        short8 b[4];
        #pragma unroll
        for (int s = 0; s < 4; ++s)
            b[s] = *(const short8*)(mp + s * 512);

        f32x4 acc[8] = {};
        #pragma unroll
        for (int s = 0; s < 4; ++s)
            #pragma unroll
            for (int jf = 0; jf < 8; ++jf)
                acc[jf] = __builtin_amdgcn_mfma_f32_16x16x32_bf16(a[jf][s], b[s], acc[jf], 0, 0, 0);

        #pragma unroll
        for (int f = 0; f < 8; ++f) {
            fv4 o;
            o.x = fmaxf(acc[f][0] + bi[f].x + h[f].x, 0.f);
            o.y = fmaxf(acc[f][1] + bi[f].y + h[f].y, 0.f);
            o.z = fmaxf(acc[f][2] + bi[f].z + h[f].z, 0.f);
            o.w = fmaxf(acc[f][3] + bi[f].w + h[f].w, 0.f);
            *(fv4*)(out + (size_t)tokr * 1024 + e0 + f * 16 + 4 * g) = o;
        }
    }
}

extern "C" void kernel_launch(void* const* d_in, const int* in_sizes, int n_in,
                              void* d_out, int out_size, void* d_ws, size_t ws_size,
                              hipStream_t stream) {
    const float* h0    = (const float*)d_in[0];
    const float* we0_w = (const float*)d_in[1];
    const float* we0_b = (const float*)d_in[2];
    const float* ws_w  = (const float*)d_in[3];
    const float* ws_b  = (const float*)d_in[4];
    const float* wm_w  = (const float*)d_in[5];
    const float* wm_b  = (const float*)d_in[6];
    const float* we1_w = (const float*)d_in[7];
    const float* we1_b = (const float*)d_in[8];
    float* out = (float*)d_out;

    unsigned*       wmf8  = (unsigned*)d_ws;             // 2 MB fp8 (row-major)
    unsigned short* we0b  = (unsigned short*)(wmf8 + 524288); // 128*1024 bf16
    unsigned short* we1b  = we0b + 131072;               // 1024*128 bf16
    unsigned short* wsb   = we1b + 131072;               // 128*128 bf16
    unsigned char*  encF8 = (unsigned char*)(wsb + 16384);     // 2 MB fp8 (tiled)
    float*          logT  = (float*)(encF8 + 2097152);   // [128][16384] f32
    unsigned short* gateT = (unsigned short*)(logT + 2097152); // 4 MB bf16 (tiled)
    unsigned short* mixT  = gateT + 2097152;             // 4 MB bf16 (tiled)

    k_convert_all<<<640, 256, 0, stream>>>(wm_w, we0_w, we1_w, ws_w, wmf8, we0b);
    k_enc<<<512, 256, 0, stream>>>(h0, we0b, wsb, we0_b, ws_b, encF8, logT);
    k_softmax0<<<128, 1024, 0, stream>>>(logT, gateT);
    k_mix<<<768, 256, 0, stream>>>((const unsigned char*)wmf8, encF8, gateT, wm_b, mixT);
    k_dec<<<512, 256, 0, stream>>>(we1b, mixT, we1_b, h0, out);
}

// Round 19
// 155.516 us; speedup vs baseline: 1.0924x; 1.0112x over previous
//
#include <hip/hip_runtime.h>

// DomDepResidualLayer: out = relu(h0 + (mixed @ we1^T + b1))
//   enc   = h0 @ we0^T + b0                         [16384,128]
//   acts  = relu(einsum('nd,mkd->mnk', enc, wm)+bm) (never materialized)
//   gate  = softmax(enc @ ws^T + bs, axis=0)        [16384,128]
//   mixed[n,i] = sum_j acts[i,n,j]*gate[n,j]        [16384,128]
// v20 = banked v19 + ONE isolated k_mix change: same-tile wave grouping.
// Block = 4 modules (wave w owns module mg*4+w) sharing ONE tile stream;
// all 4 waves (and co-resident blocks, same part) read identical enc/gate
// addresses -> L1 broadcast hits; L2 read traffic drops ~12x (~790MB -> 66MB,
// removing a ~23us L2-BW floor). Per-wave MFMA work and registers unchanged.

#define N_TOK   16384
#define EMB     1024
#define MDIM    128

typedef __attribute__((ext_vector_type(8))) short   short8;   // 8 bf16 = 1 bf16 MFMA frag
typedef __attribute__((ext_vector_type(4))) float   f32x4;
typedef __attribute__((ext_vector_type(4))) float   fv4;
typedef __attribute__((ext_vector_type(4))) unsigned short us4;

static __device__ __forceinline__ unsigned short f2bf(float f) {
    union { float f; unsigned u; } v; v.f = f;
    unsigned r = v.u + 0x7FFFu + ((v.u >> 16) & 1u);   // RNE
    return (unsigned short)(r >> 16);
}
static __device__ __forceinline__ float bf2f_lo(unsigned u) {
    union { unsigned u; float f; } v; v.u = u << 16; return v.f;
}
static __device__ __forceinline__ float bf2f_hi(unsigned u) {
    union { unsigned u; float f; } v; v.u = u & 0xffff0000u; return v.f;
}

// ---------------- fused weight conversion: wm -> fp8, we0/we1/ws -> bf16 ----------------
__global__ void k_convert_all(const float* __restrict__ wm_w,
                              const float* __restrict__ we0_w,
                              const float* __restrict__ we1_w,
                              const float* __restrict__ ws_w,
                              unsigned* __restrict__ wmf8,
                              unsigned short* __restrict__ bf16dst) {
    const int N = 524288 + 36864;
    for (int i = blockIdx.x * blockDim.x + threadIdx.x; i < N;
         i += gridDim.x * blockDim.x) {
        if (i < 524288) {                       // wm -> fp8 e4m3, 4 vals per u32
            fv4 v = *(const fv4*)(wm_w + (size_t)i * 4);
            int pk = __builtin_amdgcn_cvt_pk_fp8_f32(v.x, v.y, 0, false);
            pk = __builtin_amdgcn_cvt_pk_fp8_f32(v.z, v.w, pk, true);
            wmf8[i] = (unsigned)pk;
        } else {                                // we0|we1|ws -> bf16
            int j = i - 524288;
            const float* src;
            if (j < 32768)      src = we0_w + (size_t)j * 4;
            else if (j < 65536) src = we1_w + (size_t)(j - 32768) * 4;
            else                src = ws_w  + (size_t)(j - 65536) * 4;
            fv4 v = *(const fv4*)src;
            us4 o;
            o.x = f2bf(v.x); o.y = f2bf(v.y); o.z = f2bf(v.z); o.w = f2bf(v.w);
            *(us4*)(bf16dst + (size_t)j * 4) = o;
        }
    }
}

// encF8 fp8 tile layout (2048 B per 16-tok tile), per-lane-contiguous:
//   byte(tok, d) = tile*2048 + (((d&31)>>3)*16 + tok)*32 + (d>>5)*8 + (d&7)
// gateT bf16 tile layout (2048 bf16 per tile):
//   elem(tok, j=f*16+4g+rr) = tile*2048 + (f>>1)*512 + (g*16 + (tok&15))*8 + (f&1)*4 + rr

// ---------------- enc = h0 @ we0^T + b0 (fp8 out), fused logits = enc @ ws^T + bs ----------------
__global__ __launch_bounds__(256) void k_enc(const float* __restrict__ h0,
                                             const unsigned short* __restrict__ we0b,
                                             const unsigned short* __restrict__ wsb,
                                             const float* __restrict__ we0_bias,
                                             const float* __restrict__ ws_bias,
                                             unsigned char* __restrict__ encF8,
                                             float* __restrict__ logT) {
    __shared__ unsigned short Wt[128 * 128];
    __shared__ unsigned short Ht[32 * 128];
    __shared__ unsigned short Et[32 * 128];

    const int tid = threadIdx.x;
    const int lane = tid & 63, w = tid >> 6;
    const int c = lane & 15, g = lane >> 4;
    const int wd = w >> 1, wt = w & 1;
    const int t0 = blockIdx.x * 32;

    f32x4 acc[4] = {};
    for (int ks = 0; ks < 8; ++ks) {
        #pragma unroll
        for (int it = 0; it < 8; ++it) {
            int m = it * 256 + tid;
            int row = m >> 4, gc = m & 15;
            short8 v = *(const short8*)(we0b + row * 1024 + ks * 128 + gc * 8);
            *(short8*)&Wt[row * 128 + ((gc ^ (row & 7)) * 8)] = v;
        }
        #pragma unroll
        for (int it = 0; it < 2; ++it) {
            int m = it * 256 + tid;
            int row = m >> 4, gc = m & 15;
            const float* hp = h0 + (size_t)(t0 + row) * 1024 + ks * 128 + gc * 8;
            fv4 v0 = *(const fv4*)hp;
            fv4 v1 = *(const fv4*)(hp + 4);
            short8 ov;
            ov[0] = (short)f2bf(v0.x); ov[1] = (short)f2bf(v0.y);
            ov[2] = (short)f2bf(v0.z); ov[3] = (short)f2bf(v0.w);
            ov[4] = (short)f2bf(v1.x); ov[5] = (short)f2bf(v1.y);
            ov[6] = (short)f2bf(v1.z); ov[7] = (short)f2bf(v1.w);
            *(short8*)&Ht[row * 128 + ((gc ^ (row & 7)) * 8)] = ov;
        }
        __syncthreads();
        #pragma unroll
        for (int s = 0; s < 4; ++s) {
            int gk = s * 4 + g;
            int brow = wt * 16 + c;
            short8 b = *(const short8*)&Ht[brow * 128 + ((gk ^ (brow & 7)) * 8)];
            #pragma unroll
            for (int jf = 0; jf < 4; ++jf) {
                int j = wd * 64 + jf * 16 + c;
                short8 a = *(const short8*)&Wt[j * 128 + ((gk ^ (j & 7)) * 8)];
                acc[jf] = __builtin_amdgcn_mfma_f32_16x16x32_bf16(a, b, acc[jf], 0, 0, 0);
            }
        }
        __syncthreads();
    }
    const int tile = blockIdx.x * 2 + wt;
    const int erow = wt * 16 + c;
    #pragma unroll
    for (int f = 0; f < 4; ++f) {
        int d0 = wd * 64 + f * 16 + 4 * g;
        fv4 bi = *(const fv4*)(we0_bias + d0);
        float v0 = acc[f][0] + bi.x, v1 = acc[f][1] + bi.y;
        float v2 = acc[f][2] + bi.z, v3 = acc[f][3] + bi.w;
        // fp8 pack -> encF8
        int pk = __builtin_amdgcn_cvt_pk_fp8_f32(v0, v1, 0, false);
        pk = __builtin_amdgcn_cvt_pk_fp8_f32(v2, v3, pk, true);
        int s = wd * 2 + (f >> 1);
        int chunk = (f & 1) * 2 + (g >> 1);
        int e = (g & 1) * 4;
        *(unsigned*)(encF8 + (size_t)tile * 2048 + (chunk * 16 + c) * 32 + s * 8 + e) = (unsigned)pk;
        // bf16 -> LDS Et for fused logits
        us4 o;
        o.x = f2bf(v0); o.y = f2bf(v1); o.z = f2bf(v2); o.w = f2bf(v3);
        int cg = d0 >> 3, off = d0 & 7;
        *(us4*)&Et[erow * 128 + ((cg ^ (erow & 7)) * 8) + off] = o;
    }
    __syncthreads();

    short8 al[4][4];
    #pragma unroll
    for (int jf = 0; jf < 4; ++jf)
        #pragma unroll
        for (int s = 0; s < 4; ++s)
            al[jf][s] = *(const short8*)(wsb + (wd * 64 + jf * 16 + c) * 128 + s * 32 + g * 8);
    short8 bl[4];
    #pragma unroll
    for (int s = 0; s < 4; ++s) {
        int cg2 = s * 4 + g;
        bl[s] = *(const short8*)&Et[erow * 128 + ((cg2 ^ (erow & 7)) * 8)];
    }
    f32x4 acc2[4] = {};
    #pragma unroll
    for (int s = 0; s < 4; ++s)
        #pragma unroll
        for (int jf = 0; jf < 4; ++jf)
            acc2[jf] = __builtin_amdgcn_mfma_f32_16x16x32_bf16(al[jf][s], bl[s], acc2[jf], 0, 0, 0);
    const int tokc = t0 + wt * 16 + c;
    #pragma unroll
    for (int jf = 0; jf < 4; ++jf) {
        int m0 = wd * 64 + jf * 16 + 4 * g;
        fv4 bs = *(const fv4*)(ws_bias + m0);
        logT[(size_t)(m0 + 0) * N_TOK + tokc] = acc2[jf][0] + bs.x;
        logT[(size_t)(m0 + 1) * N_TOK + tokc] = acc2[jf][1] + bs.y;
        logT[(size_t)(m0 + 2) * N_TOK + tokc] = acc2[jf][2] + bs.z;
        logT[(size_t)(m0 + 3) * N_TOK + tokc] = acc2[jf][3] + bs.w;
    }
}

// ---------------- gate = softmax over axis 0, per column m (bf16, tiled) ----------------
__global__ __launch_bounds__(1024) void k_softmax0(const float* __restrict__ logT,
                                                   unsigned short* __restrict__ gateT) {
    __shared__ float red[32];
    const int m = blockIdx.x;
    const int tid = threadIdx.x;
    const int lane = tid & 63, wv = tid >> 6;   // 16 waves
    const float* row = logT + (size_t)m * N_TOK;

    fv4 v[4];
    float vmax = -3.0e38f;
    #pragma unroll
    for (int it = 0; it < 4; ++it) {
        v[it] = *(const fv4*)(row + it * 4096 + tid * 4);
        vmax = fmaxf(vmax, fmaxf(fmaxf(v[it].x, v[it].y), fmaxf(v[it].z, v[it].w)));
    }
    #pragma unroll
    for (int o = 32; o > 0; o >>= 1) vmax = fmaxf(vmax, __shfl_xor(vmax, o));
    if (lane == 0) red[wv] = vmax;
    __syncthreads();
    float bmax = -3.0e38f;
    #pragma unroll
    for (int k = 0; k < 16; ++k) bmax = fmaxf(bmax, red[k]);

    float s = 0.f;
    #pragma unroll
    for (int it = 0; it < 4; ++it) {
        v[it].x = __expf(v[it].x - bmax); v[it].y = __expf(v[it].y - bmax);
        v[it].z = __expf(v[it].z - bmax); v[it].w = __expf(v[it].w - bmax);
        s += v[it].x + v[it].y + v[it].z + v[it].w;
    }
    #pragma unroll
    for (int o = 32; o > 0; o >>= 1) s += __shfl_xor(s, o);
    if (lane == 0) red[16 + wv] = s;
    __syncthreads();
    float bs = 0.f;
    #pragma unroll
    for (int k = 0; k < 16; ++k) bs += red[16 + k];
    const float inv = 1.f / bs;

    const int q  = m >> 5;
    const int w8 = ((m >> 4) & 1) * 4 + (m & 3);
    const int gl = ((m & 15) >> 2) * 16;
    #pragma unroll
    for (int it = 0; it < 4; ++it) {
        int t = it * 4096 + tid * 4;
        float pv[4] = { v[it].x * inv, v[it].y * inv, v[it].z * inv, v[it].w * inv };
        #pragma unroll
        for (int k = 0; k < 4; ++k) {
            int tok = t + k;
            gateT[(size_t)(tok >> 4) * 2048 + q * 512 + (gl + (tok & 15)) * 8 + w8] = f2bf(pv[k]);
        }
    }
}

// ---------------- k_mix: fp8 reg panel, 3 waves/SIMD, SAME-TILE wave grouping ----------------
// grid 768: mg = bid&31 (module group of 4), part = bid>>5 in [0,24).
// Wave w owns module i = mg*4+w; ALL waves process the same tile each
// iteration (shared enc/gate addresses -> L1 broadcast). Part p covers
// tiles [p*42+min(p,16), +42+(p<16)).
__global__ __launch_bounds__(256)
__attribute__((amdgpu_waves_per_eu(3, 3)))
void k_mix(const unsigned char* __restrict__ wmf8,
           const unsigned char* __restrict__ encF8,
           const unsigned short* __restrict__ gateT,
           const float* __restrict__ wm_bias,
           unsigned short* __restrict__ mixT) {
    const int bid = blockIdx.x;
    const int mg = bid & 31, part = bid >> 5;
    const int tid = threadIdx.x;
    const int lane = tid & 63, w = tid >> 6;
    const int c = lane & 15, g = lane >> 4;
    const int i = mg * 4 + w;

    const unsigned char* wmi = wmf8 + (size_t)i * 16384;
    uint2 a[8][4];
    #pragma unroll
    for (int jf = 0; jf < 8; ++jf)
        #pragma unroll
        for (int s = 0; s < 4; ++s) {
            a[jf][s] = *(const uint2*)(wmi + (jf * 16 + c) * 128 + s * 32 + g * 8);
            asm volatile("" : "+v"(a[jf][s]));
        }
    f32x4 bias4[8];
    #pragma unroll
    for (int f = 0; f < 8; ++f) {
        bias4[f] = *(const f32x4*)(wm_bias + i * 128 + f * 16 + 4 * g);
        asm volatile("" : "+v"(bias4[f]));
    }

    const int start = part * 42 + (part < 16 ? part : 16);
    const int cnt = 42 + (part < 16 ? 1 : 0);
    const int si = i >> 5, ch = (i & 31) >> 3, ei = i & 7;

    const unsigned char* encB = encF8 + (size_t)start * 2048 + lane * 32;
    const unsigned* gateB = (const unsigned*)(gateT + (size_t)start * 2048) + lane * 4;
    unsigned short* mixB = mixT + (size_t)start * 2048 + si * 512 + (ch * 16 + lane) * 8 + ei;

    // prologue: enc frag for t=0
    uint4 q0 = *(const uint4*)(encB);
    uint4 q1 = *(const uint4*)(encB + 16);

    #pragma unroll 1
    for (int t = 0; t < cnt; ++t) {
        // gate loads for CURRENT tile: latency hides under the MFMA block
        const unsigned* gp = gateB + (size_t)t * 1024;
        uint4 G0 = *(const uint4*)(gp);
        uint4 G1 = *(const uint4*)(gp + 256);
        uint4 G2 = *(const uint4*)(gp + 512);
        uint4 G3 = *(const uint4*)(gp + 768);

        long b0 = __builtin_bit_cast(long, (uint2){q0.x, q0.y});
        long b1 = __builtin_bit_cast(long, (uint2){q0.z, q0.w});
        long b2 = __builtin_bit_cast(long, (uint2){q1.x, q1.y});
        long b3 = __builtin_bit_cast(long, (uint2){q1.z, q1.w});

        __builtin_amdgcn_s_setprio(1);
        f32x4 acc[8];
        #pragma unroll
        for (int jf = 0; jf < 8; ++jf)
            acc[jf] = __builtin_amdgcn_mfma_f32_16x16x32_fp8_fp8(
                __builtin_bit_cast(long, a[jf][0]), b0, bias4[jf], 0, 0, 0);
        #pragma unroll
        for (int jf = 0; jf < 8; ++jf)
            acc[jf] = __builtin_amdgcn_mfma_f32_16x16x32_fp8_fp8(
                __builtin_bit_cast(long, a[jf][1]), b1, acc[jf], 0, 0, 0);
        #pragma unroll
        for (int jf = 0; jf < 8; ++jf)
            acc[jf] = __builtin_amdgcn_mfma_f32_16x16x32_fp8_fp8(
                __builtin_bit_cast(long, a[jf][2]), b2, acc[jf], 0, 0, 0);
        #pragma unroll
        for (int jf = 0; jf < 8; ++jf)
            acc[jf] = __builtin_amdgcn_mfma_f32_16x16x32_fp8_fp8(
                __builtin_bit_cast(long, a[jf][3]), b3, acc[jf], 0, 0, 0);
        __builtin_amdgcn_s_setprio(0);

        // prefetch next tile's enc frag (consumed next iteration)
        {
            const int tn = (t + 1 < cnt) ? t + 1 : t;
            const unsigned char* ebn = encB + (size_t)tn * 2048;
            q0 = *(const uint4*)(ebn);
            q1 = *(const uint4*)(ebn + 16);
        }

        float p0 = 0.f, p1 = 0.f, p2 = 0.f, p3 = 0.f;
        #define EPI(F, GA, GB) {                                        \
            p0 += fmaxf(acc[F][0], 0.f) * bf2f_lo(GA);                  \
            p1 += fmaxf(acc[F][1], 0.f) * bf2f_hi(GA);                  \
            p2 += fmaxf(acc[F][2], 0.f) * bf2f_lo(GB);                  \
            p3 += fmaxf(acc[F][3], 0.f) * bf2f_hi(GB);                  \
        }
        EPI(0, G0.x, G0.y) EPI(1, G0.z, G0.w)
        EPI(2, G1.x, G1.y) EPI(3, G1.z, G1.w)
        EPI(4, G2.x, G2.y) EPI(5, G2.z, G2.w)
        EPI(6, G3.x, G3.y) EPI(7, G3.z, G3.w)
        #undef EPI
        float p = (p0 + p1) + (p2 + p3);
        p += __shfl_xor(p, 16);
        p += __shfl_xor(p, 32);
        if (lane < 16) *(mixB + (size_t)t * 2048) = f2bf(p);
    }
}

// ---------------- out = relu(mixed @ we1^T + b1 + h0) ----------------
// grid 512 = 8 eb x 64 tg (256 tokens each, t<4).
__global__ __launch_bounds__(256)
__attribute__((amdgpu_waves_per_eu(2, 2)))
void k_dec(const unsigned short* __restrict__ we1b,
           const unsigned short* __restrict__ mixT,
           const float* __restrict__ we1_bias,
           const float* __restrict__ h0,
           float* __restrict__ out) {
    const int bid = blockIdx.x;
    const int eb = bid & 7, tg = bid >> 3;
    const int e0 = eb * 128;
    const int tid = threadIdx.x;
    const int lane = tid & 63, w = tid >> 6;
    const int c = lane & 15, g = lane >> 4;

    short8 a[8][4];
    #pragma unroll
    for (int jf = 0; jf < 8; ++jf)
        #pragma unroll
        for (int s = 0; s < 4; ++s) {
            a[jf][s] = *(const short8*)(we1b + (size_t)(e0 + jf * 16 + c) * 128 + s * 32 + g * 8);
            asm volatile("" : "+v"(a[jf][s]));
        }
    fv4 bi[8];
    #pragma unroll
    for (int f = 0; f < 8; ++f)
        bi[f] = *(const fv4*)(we1_bias + e0 + f * 16 + 4 * g);

    #pragma unroll 1
    for (int t = 0; t < 4; ++t) {
        const int tokr = tg * 256 + t * 64 + w * 16 + c;
        const int tile = tg * 16 + t * 4 + w;
        fv4 h[8];
        #pragma unroll
        for (int f = 0; f < 8; ++f)
            h[f] = *(const fv4*)(h0 + (size_t)tokr * 1024 + e0 + f * 16 + 4 * g);
        const unsigned short* mp = mixT + (size_t)tile * 2048 + lane * 8;
        short8 b[4];
        #pragma unroll
        for (int s = 0; s < 4; ++s)
            b[s] = *(const short8*)(mp + s * 512);

        f32x4 acc[8] = {};
        #pragma unroll
        for (int s = 0; s < 4; ++s)
            #pragma unroll
            for (int jf = 0; jf < 8; ++jf)
                acc[jf] = __builtin_amdgcn_mfma_f32_16x16x32_bf16(a[jf][s], b[s], acc[jf], 0, 0, 0);

        #pragma unroll
        for (int f = 0; f < 8; ++f) {
            fv4 o;
            o.x = fmaxf(acc[f][0] + bi[f].x + h[f].x, 0.f);
            o.y = fmaxf(acc[f][1] + bi[f].y + h[f].y, 0.f);
            o.z = fmaxf(acc[f][2] + bi[f].z + h[f].z, 0.f);
            o.w = fmaxf(acc[f][3] + bi[f].w + h[f].w, 0.f);
            *(fv4*)(out + (size_t)tokr * 1024 + e0 + f * 16 + 4 * g) = o;
        }
    }
}

extern "C" void kernel_launch(void* const* d_in, const int* in_sizes, int n_in,
                              void* d_out, int out_size, void* d_ws, size_t ws_size,
                              hipStream_t stream) {
    const float* h0    = (const float*)d_in[0];
    const float* we0_w = (const float*)d_in[1];
    const float* we0_b = (const float*)d_in[2];
    const float* ws_w  = (const float*)d_in[3];
    const float* ws_b  = (const float*)d_in[4];
    const float* wm_w  = (const float*)d_in[5];
    const float* wm_b  = (const float*)d_in[6];
    const float* we1_w = (const float*)d_in[7];
    const float* we1_b = (const float*)d_in[8];
    float* out = (float*)d_out;

    unsigned*       wmf8  = (unsigned*)d_ws;             // 2 MB fp8 (row-major)
    unsigned short* we0b  = (unsigned short*)(wmf8 + 524288); // 128*1024 bf16
    unsigned short* we1b  = we0b + 131072;               // 1024*128 bf16
    unsigned short* wsb   = we1b + 131072;               // 128*128 bf16
    unsigned char*  encF8 = (unsigned char*)(wsb + 16384);     // 2 MB fp8 (tiled)
    float*          logT  = (float*)(encF8 + 2097152);   // [128][16384] f32
    unsigned short* gateT = (unsigned short*)(logT + 2097152); // 4 MB bf16 (tiled)
    unsigned short* mixT  = gateT + 2097152;             // 4 MB bf16 (tiled)

    k_convert_all<<<640, 256, 0, stream>>>(wm_w, we0_w, we1_w, ws_w, wmf8, we0b);
    k_enc<<<512, 256, 0, stream>>>(h0, we0b, wsb, we0_b, ws_b, encF8, logT);
    k_softmax0<<<128, 1024, 0, stream>>>(logT, gateT);
    k_mix<<<768, 256, 0, stream>>>((const unsigned char*)wmf8, encF8, gateT, wm_b, mixT);
    k_dec<<<512, 256, 0, stream>>>(we1b, mixT, we1_b, h0, out);
}